// Round 11
// baseline (107.798 us; speedup 1.0000x reference)
//
#include <hip/hip_runtime.h>
#include <math.h>

// NormalLoss: for each template vertex (M=6890), take the K=15 scan points
// (N=20000) with LARGEST distance, among them pick the min-angle normal
// match, loss = mean ||sv[sel]-tv||.
//
// Round-11 design (r7/r8/r10 all regressed vs r6 -> r6's event machinery is
// the op-count local optimum; attack LATENCY and NODES instead):
//  * main kernel: TWO vertices per wave, time-interleaved (ILP). One shared
//    point load feeds both d2 chains (load traffic per vertex halves);
//    bootstrap = sort64_pair (two independent bitonic networks in one body,
//    back-to-back shuffles fill the LDS-pipe latency); event loops are r6's
//    body verbatim, run per vertex. No end-of-block barrier (waves write
//    partial[] directly).
//  * prep: hist MERGED into scan_scatter -- each of the 79 blocks reads all
//    N points itself and builds histTotal + histBefore(base) in LDS, so no
//    blkhist round-trip and one fewer graph node.
//  * tie-breaks everywhere explicit on (d2 desc, origIdx asc); thr >= keeps
//    boundary ties; smax = bucket-edge suffix bound (order-independent).
//    Exact jax top_k + argmin-first-occurrence semantics (absmax 0.0 x9).

constexpr int K = 15;
constexpr int NBUCK = 256;

__device__ __forceinline__ int bucket_of(float k2) {
    int b = (int)(k2 * 8.0f);           // 0.125-wide buckets over |p|^2 in [0,32)
    b = b > (NBUCK - 1) ? (NBUCK - 1) : b;
    return (NBUCK - 1) - b;             // bucket 0 = largest |p|
}

// One self-sufficient prep kernel: every block redundantly histograms ALL N
// points (L1/L2-resident), computes bucket starts + its own per-bucket base,
// scatters its 256-point slice. Block 0 also writes smax.
__global__ __launch_bounds__(256) void prep_kernel(
    const float* __restrict__ sv,
    float4*      __restrict__ sorted,   // [N] out: (x,y,z,bitcast(origIdx))
    float*       __restrict__ smax,     // [nb] out: |p| bound at pos >= j*64
    int N, int nb)
{
    __shared__ int histT[NBUCK];   // total count per bucket
    __shared__ int histB[NBUCK];   // count among points with idx < my base
    __shared__ int tmp[NBUCK];
    __shared__ int startSh[NBUCK];
    __shared__ int cursor[NBUCK];
    const int t    = threadIdx.x;
    const int base = blockIdx.x * 256;

    histT[t] = 0; histB[t] = 0;
    __syncthreads();
    for (int i = t; i < N; i += 256) {
        float x = sv[3*i], y = sv[3*i+1], z = sv[3*i+2];
        int b = bucket_of(fmaf(x, x, fmaf(y, y, z*z)));
        atomicAdd(&histT[b], 1);
        if (i < base) atomicAdd(&histB[b], 1);
    }
    __syncthreads();

    // Kogge-Stone inclusive scan of histT -> bucket starts
    tmp[t] = histT[t];
    __syncthreads();
    for (int d = 1; d < NBUCK; d <<= 1) {
        int u = (t >= d) ? tmp[t - d] : 0;
        __syncthreads();
        tmp[t] += u;
        __syncthreads();
    }
    int startv = tmp[t] - histT[t];
    startSh[t] = startv;
    cursor[t]  = startv + histB[t];     // my block's write base per bucket
    __syncthreads();

    if (blockIdx.x == 0) {
        // smax[j]: position j*64 lies in flipped bucket fb (largest fb with
        // start[fb] <= pos); all later points have |p| <= bucket upper edge.
        for (int j = t; j < nb; j += 256) {
            int pos = j * 64;
            int lo = 0, hi = NBUCK - 1;
            while (lo < hi) {
                int mid = (lo + hi + 1) >> 1;
                if (startSh[mid] <= pos) lo = mid; else hi = mid - 1;
            }
            int bOrig = (NBUCK - 1) - lo;
            smax[j] = sqrtf((float)(bOrig + 1) * 0.125f);
        }
    }

    int i = base + t;
    if (i < N) {
        float x = sv[3*i], y = sv[3*i+1], z = sv[3*i+2];
        float k2 = fmaf(x, x, fmaf(y, y, z*z));
        int pos = atomicAdd(&cursor[bucket_of(k2)], 1);   // LDS atomic
        sorted[pos] = make_float4(x, y, z, __int_as_float(i));
    }
}

// Two independent 64-lane bitonic sorts, interleaved for ILP.
// Descending by (v desc, idx asc) — strict total order.
__device__ __forceinline__ void sort64_pair(float& v0, int& i0,
                                            float& v1, int& i1, int lane) {
#pragma unroll
    for (int k = 2; k <= 64; k <<= 1) {
#pragma unroll
        for (int j = k >> 1; j > 0; j >>= 1) {
            float ov0 = __shfl_xor(v0, j);
            float ov1 = __shfl_xor(v1, j);
            int   oi0 = __shfl_xor(i0, j);
            int   oi1 = __shfl_xor(i1, j);
            bool up    = ((lane & k) == 0);
            bool lower = ((lane & j) == 0);
            bool mine0 = (v0 > ov0) || (v0 == ov0 && i0 < oi0);
            bool keep0 = lower ? (up ? mine0 : !mine0) : (up ? !mine0 : mine0);
            if (!keep0) { v0 = ov0; i0 = oi0; }
            bool mine1 = (v1 > ov1) || (v1 == ov1 && i1 < oi1);
            bool keep1 = lower ? (up ? mine1 : !mine1) : (up ? !mine1 : mine1);
            if (!keep1) { v1 = ov1; i1 = oi1; }
        }
    }
}

template<bool SORTED>
__global__ __launch_bounds__(256) void knn_loss_kernel(
    const float4* __restrict__ pts,   // sorted points (SORTED only)
    const float*  __restrict__ smax,  // suffix |p| upper bound per 64-block
    const float*  __restrict__ sv,    // [N,3] original scan vertices
    const float*  __restrict__ tv,    // [M,3]
    const float*  __restrict__ sn,    // [N,3]
    const float*  __restrict__ tn,    // [M,3]
    float* __restrict__ partial,      // [M] per-vertex contributions
    int N, int M, float invM)
{
    const int lane   = threadIdx.x & 63;
    const int w      = threadIdx.x >> 6;
    const int waveId = blockIdx.x * 4 + w;
    const int m0r = waveId * 2, m1r = waveId * 2 + 1;
    const bool val0 = (m0r < M), val1 = (m1r < M);
    const int m0 = val0 ? m0r : M - 1;     // duplicate compute, write suppressed
    const int m1 = val1 ? m1r : M - 1;

    const float t0x = tv[3*m0], t0y = tv[3*m0+1], t0z = tv[3*m0+2];
    const float t1x = tv[3*m1], t1y = tv[3*m1+1], t1z = tv[3*m1+2];
    const float tlen0 = sqrtf(t0x*t0x + t0y*t0y + t0z*t0z);
    const float tlen1 = sqrtf(t1x*t1x + t1y*t1y + t1z*t1z);

    // ---- bootstrap: paired bitonic sort of first 64 points ----
    float v0, v1; int i0, i1;
    {
        int l = (lane < N) ? lane : 0;
        float px, py, pz; int idx;
        if (SORTED) {
            float4 q = pts[l];
            px = q.x; py = q.y; pz = q.z; idx = __float_as_int(q.w);
        } else {
            px = sv[3*l]; py = sv[3*l+1]; pz = sv[3*l+2]; idx = l;
        }
        float dx = px - t0x, dy = py - t0y, dz = pz - t0z;
        v0 = fmaf(dx, dx, fmaf(dy, dy, dz * dz));
        dx = px - t1x; dy = py - t1y; dz = pz - t1z;
        v1 = fmaf(dx, dx, fmaf(dy, dy, dz * dz));
        i0 = idx; i1 = idx;
        if (lane >= N) { v0 = -1.0f; i0 = 0x7FFFFFFF; v1 = -1.0f; i1 = 0x7FFFFFFF; }
    }
    sort64_pair(v0, i0, v1, i1, lane);
    float eV0 = (lane < K) ? v0 : -1.0f;  int eI0 = i0;
    float eV1 = (lane < K) ? v1 : -1.0f;  int eI1 = i1;
    float thr0 = __shfl(v0, K - 1);
    float thr1 = __shfl(v1, K - 1);
    bool done0 = false, done1 = false;

    // ---- main scan: shared loads, two independent candidate streams ----
    for (int ib = 64; ib < N; ib += 64) {
        int  i   = ib + lane;
        bool has = (i < N);
        float4 q;
        float d20, d21; int oi2;
        if (SORTED) {
            q = pts[has ? i : 0];                    // load first (overlaps smax)
            float bnd = smax[ib >> 6];               // d <= |p| + |tv|
            done0 = done0 || ((bnd + tlen0) * (bnd + tlen0) * 1.00001f < thr0);
            done1 = done1 || ((bnd + tlen1) * (bnd + tlen1) * 1.00001f < thr1);
            if (done0 && done1) break;
            float dx = q.x - t0x, dy = q.y - t0y, dz = q.z - t0z;
            d20 = fmaf(dx, dx, fmaf(dy, dy, dz * dz));
            dx = q.x - t1x; dy = q.y - t1y; dz = q.z - t1z;
            d21 = fmaf(dx, dx, fmaf(dy, dy, dz * dz));
            oi2 = __float_as_int(q.w);
        } else {
            int g = has ? i : 0;
            float px = sv[3*g], py = sv[3*g+1], pz = sv[3*g+2];
            float dx = px - t0x, dy = py - t0y, dz = pz - t0z;
            d20 = fmaf(dx, dx, fmaf(dy, dy, dz * dz));
            dx = px - t1x; dy = py - t1y; dz = pz - t1z;
            d21 = fmaf(dx, dx, fmaf(dy, dy, dz * dz));
            oi2 = i;
        }
        // ---- vertex 0 events (r6-verbatim body) ----
        // done0 => no candidate can pass (d <= bnd < needed), guard is free
        unsigned long long mb = done0 ? 0ull : __ballot(has && (d20 >= thr0));
        while (mb) {
            int src = __ffsll(mb) - 1;
            mb &= mb - 1;
            float cv = __shfl(d20, src);
            int   ci = __shfl(oi2, src);
            unsigned long long bb =
                __ballot((eV0 > cv) || (eV0 == cv && eI0 < ci)) & 0x7FFFull;
            int p = __popcll(bb);
            if (p < K) {   // wave-uniform
                float uv = __shfl_up(eV0, 1);
                int   ui = __shfl_up(eI0, 1);
                if (lane < K) {
                    if (lane == p)      { eV0 = cv; eI0 = ci; }
                    else if (lane > p)  { eV0 = uv; eI0 = ui; }
                }
                thr0 = __shfl(eV0, K - 1);       // tighten + prune doomed
                if (mb) mb &= __ballot(d20 >= thr0);
            }
        }
        // ---- vertex 1 events ----
        mb = done1 ? 0ull : __ballot(has && (d21 >= thr1));
        while (mb) {
            int src = __ffsll(mb) - 1;
            mb &= mb - 1;
            float cv = __shfl(d21, src);
            int   ci = __shfl(oi2, src);
            unsigned long long bb =
                __ballot((eV1 > cv) || (eV1 == cv && eI1 < ci)) & 0x7FFFull;
            int p = __popcll(bb);
            if (p < K) {
                float uv = __shfl_up(eV1, 1);
                int   ui = __shfl_up(eI1, 1);
                if (lane < K) {
                    if (lane == p)      { eV1 = cv; eI1 = ci; }
                    else if (lane > p)  { eV1 = uv; eI1 = ui; }
                }
                thr1 = __shfl(eV1, K - 1);
                if (mb) mb &= __ballot(d21 >= thr1);
            }
        }
    }

    // ---- epilogue: per-vertex argmin angle, tie-break by rank (= lane) ----
    float ang0 = 3.0e38f, ang1 = 3.0e38f;
    if (lane < K && eI0 != 0x7FFFFFFF) {
        float tnx = tn[3*m0], tny = tn[3*m0+1], tnz = tn[3*m0+2];
        float dot = sn[3*eI0]*tnx + sn[3*eI0+1]*tny + sn[3*eI0+2]*tnz;
        dot = fminf(1.0f, fmaxf(-1.0f, dot));
        ang0 = acosf(dot) * 57.29577951308232f;   // degrees, matches jnp
    }
    if (lane < K && eI1 != 0x7FFFFFFF) {
        float tnx = tn[3*m1], tny = tn[3*m1+1], tnz = tn[3*m1+2];
        float dot = sn[3*eI1]*tnx + sn[3*eI1+1]*tny + sn[3*eI1+2]*tnz;
        dot = fminf(1.0f, fmaxf(-1.0f, dot));
        ang1 = acosf(dot) * 57.29577951308232f;
    }
    float ba0 = ang0; int br0 = lane; int bi0 = eI0;
    float ba1 = ang1; int br1 = lane; int bi1 = eI1;
#pragma unroll
    for (int s = 1; s < 16; s <<= 1) {
        float oa0  = __shfl_xor(ba0, s);
        float oa1  = __shfl_xor(ba1, s);
        int   or0  = __shfl_xor(br0, s);
        int   or1  = __shfl_xor(br1, s);
        int   ob0  = __shfl_xor(bi0, s);
        int   ob1  = __shfl_xor(bi1, s);
        bool take0 = (oa0 < ba0) || (oa0 == ba0 && or0 < br0);
        if (take0) { ba0 = oa0; br0 = or0; bi0 = ob0; }
        bool take1 = (oa1 < ba1) || (oa1 == ba1 && or1 < br1);
        if (take1) { ba1 = oa1; br1 = or1; bi1 = ob1; }
    }
    if (lane == 0) {
        if (val0) {
            float dx = sv[3*bi0] - t0x, dy = sv[3*bi0+1] - t0y, dz = sv[3*bi0+2] - t0z;
            partial[m0] = sqrtf(dx*dx + dy*dy + dz*dz) * invM;
        }
        if (val1) {
            float dx = sv[3*bi1] - t1x, dy = sv[3*bi1+1] - t1y, dz = sv[3*bi1+2] - t1z;
            partial[m1] = sqrtf(dx*dx + dy*dy + dz*dz) * invM;
        }
    }
}

__global__ __launch_bounds__(256) void reduce_kernel(
    const float* __restrict__ partial, float* __restrict__ out, int n)
{
    __shared__ float sh[4];
    const int lane = threadIdx.x & 63;
    const int w    = threadIdx.x >> 6;
    float s = 0.0f;
    for (int i = threadIdx.x; i < n; i += 256) s += partial[i];
#pragma unroll
    for (int d = 1; d < 64; d <<= 1) s += __shfl_xor(s, d);
    if (lane == 0) sh[w] = s;
    __syncthreads();
    if (threadIdx.x == 0) out[0] = sh[0] + sh[1] + sh[2] + sh[3];
}

extern "C" void kernel_launch(void* const* d_in, const int* in_sizes, int n_in,
                              void* d_out, int out_size, void* d_ws, size_t ws_size,
                              hipStream_t stream) {
    const float* sv = (const float*)d_in[0];   // scan_vertices   [1,N,3]
    const float* tv = (const float*)d_in[1];   // template_vertices [1,M,3]
    const float* sn = (const float*)d_in[2];   // scan_normals    [N,3]
    const float* tn = (const float*)d_in[3];   // template_normals [M,3]
    // d_in[4] = K_knn (fixed 15, compile-time)

    int N = in_sizes[0] / 3;
    int M = in_sizes[1] / 3;
    int nb = (N + 63) / 64;
    float* out = (float*)d_out;
    float invM = 1.0f / (float)M;
    int nblk  = (N + 255) / 256;
    int gridM = (M + 7) / 8;     // 4 waves/block x 2 vertices/wave

    // d_ws layout: [sorted float4 x N][smax x nb][partial x M]
    size_t offSorted  = 0;
    size_t offSmax    = offSorted + (size_t)N * sizeof(float4);
    size_t offPartial = (offSmax + (size_t)nb * sizeof(float) + 15) & ~(size_t)15;
    size_t need       = offPartial + (size_t)M * sizeof(float);

    if (ws_size >= need) {
        float4* sorted  = (float4*)((char*)d_ws + offSorted);
        float*  smax    = (float*) ((char*)d_ws + offSmax);
        float*  partial = (float*) ((char*)d_ws + offPartial);

        prep_kernel        <<<nblk, 256, 0, stream>>>(sv, sorted, smax, N, nb);
        knn_loss_kernel<true><<<gridM, 256, 0, stream>>>(
            sorted, smax, sv, tv, sn, tn, partial, N, M, invM);
        reduce_kernel      <<<1, 256, 0, stream>>>(partial, out, M);
    } else {
        float* partial = (float*)d_ws;
        knn_loss_kernel<false><<<gridM, 256, 0, stream>>>(
            nullptr, nullptr, sv, tv, sn, tn, partial, N, M, invM);
        reduce_kernel      <<<1, 256, 0, stream>>>(partial, out, M);
    }
}